// Round 4
// baseline (519.270 us; speedup 1.0000x reference)
//
#include <hip/hip_runtime.h>
#include <hip/hip_bf16.h>
#include <math.h>

#define TOK   4096
#define DIM   1024
#define DMLP  4096
#define NE    8
#define BM    256
#define BN    128
#define BK    64
#define NTHR  512
#define PADMAX (TOK + NE * BM)   // 6144 padded slots (segments 256-aligned)
#define NTILES (PADMAX / BM)     // 24 row-tiles
#define KSPLIT 4
#define KCHUNK (DMLP / KSPLIT)   // 1024

typedef __attribute__((ext_vector_type(8))) short  short8;
typedef __attribute__((ext_vector_type(4))) float  float4v;
typedef __attribute__((ext_vector_type(4))) unsigned short ushort4v;

// async global->LDS, 16 B per lane; LDS dest is wave-uniform base + lane*16
#define ASYNC16(gp, lp) __builtin_amdgcn_global_load_lds( \
    (const __attribute__((address_space(1))) unsigned int*)(gp), \
    (__attribute__((address_space(3))) unsigned int*)(lp), 16, 0, 0)

// swizzled granule offset (shorts) for row R, k-chunk C (granule = 8 bf16 = 16 B)
// 8 granules per row (BK=64); proven conflict-free in R3 (SQ_LDS_BANK_CONFLICT=0)
#define FRAG_OFF(R, C) (((((R) << 3) + ((C) ^ ((R) & 7)))) << 3)

static __device__ __forceinline__ unsigned short f2bf(float f) {
  unsigned u = __float_as_uint(f);
  u += 0x7fffu + ((u >> 16) & 1u);
  return (unsigned short)(u >> 16);
}

// exact-erf GELU via A&S 7.1.26 (|erf err| <= 1.5e-7), ~14 VALU incl v_exp/v_rcp
static __device__ __forceinline__ float gelu_f(float v) {
  const float s = v * 0.7071067811865475f;
  const float a = fabsf(s);
  const float t = __builtin_amdgcn_rcpf(1.0f + 0.3275911f * a);
  float p = 1.061405429f;
  p = p * t - 1.453152027f;
  p = p * t + 1.421413741f;
  p = p * t - 0.284496736f;
  p = p * t + 0.254829592f;
  p = p * t;
  const float e = __expf(-s * s);
  float er = 1.0f - p * e;
  er = copysignf(er, s);
  return 0.5f * v * (1.0f + er);
}

// ---------------------------------------------------------------------------
// Kernel 1: group tokens by expert (single block), segments padded to BM=256.
// ---------------------------------------------------------------------------
__global__ void group_kernel(const int* __restrict__ eidx,
                             int* __restrict__ perm,
                             int* __restrict__ tile_e) {
  __shared__ int cnt[NE], off[NE], len[NE], cur[NE];
  const int tid = threadIdx.x;
  if (tid < NE) cnt[tid] = 0;
  __syncthreads();
  for (int i = tid; i < TOK; i += 256) atomicAdd(&cnt[eidx[i]], 1);
  __syncthreads();
  if (tid == 0) {
    int o = 0;
    for (int e = 0; e < NE; e++) {
      off[e] = o;
      len[e] = ((cnt[e] + BM - 1) / BM) * BM;
      cur[e] = o;
      o += len[e];
    }
  }
  __syncthreads();
  for (int s = tid; s < PADMAX; s += 256) perm[s] = -1;
  __syncthreads();
  for (int i = tid; i < TOK; i += 256) {
    const int e = eidx[i];
    const int p = atomicAdd(&cur[e], 1);
    perm[p] = i;
  }
  __syncthreads();
  for (int t = tid; t < NTILES; t += 256) {
    const int row = t * BM;
    int te = -1;
    for (int e = 0; e < NE; e++)
      if (row >= off[e] && row < off[e] + len[e]) te = e;
    tile_e[t] = te;
  }
}

// ---------------------------------------------------------------------------
// Kernel 2: zero the output (gemm2 accumulates with atomics).
// ---------------------------------------------------------------------------
__global__ __launch_bounds__(256)
void zero_out_kernel(float* __restrict__ out) {
  const int i = blockIdx.x * 256 + threadIdx.x;
  *(float4v*)(out + (size_t)i * 4) = (float4v){0.f, 0.f, 0.f, 0.f};
}

// ---------------------------------------------------------------------------
// Kernel 3: transpose+convert W [E][K][N] f32 -> WT [E][N][K] bf16.
// 64x64 tiles, float4 coalesced reads, 16B coalesced writes.
// ---------------------------------------------------------------------------
__global__ __launch_bounds__(256)
void convtrans_kernel(const float* __restrict__ W, unsigned short* __restrict__ WT,
                      int K, int N) {
  __shared__ unsigned short T[64][68];   // 136B rows (8B aligned)
  const int e  = blockIdx.z;
  const int k0 = blockIdx.y * 64, n0 = blockIdx.x * 64;
  const float* Win = W + (size_t)e * K * N;
  unsigned short* Wout = WT + (size_t)e * K * N;
  const int tid = threadIdx.x;

  const int klb = tid >> 4;          // 0..15
  const int n4  = (tid & 15) * 4;
#pragma unroll
  for (int r = 0; r < 4; r++) {
    const int kl = klb + r * 16;
    const float4v v = *(const float4v*)(Win + (size_t)(k0 + kl) * N + n0 + n4);
#pragma unroll
    for (int q = 0; q < 4; q++) T[n4 + q][kl] = f2bf(v[q]);
  }
  __syncthreads();

  const int nlb = tid >> 3;          // 0..31
  const int kc  = (tid & 7) * 8;
#pragma unroll
  for (int w = 0; w < 2; w++) {
    const int nl = nlb + w * 32;
    const ushort4v u0 = *(const ushort4v*)&T[nl][kc];
    const ushort4v u1 = *(const ushort4v*)&T[nl][kc + 4];
    short8 o;
#pragma unroll
    for (int q = 0; q < 4; q++) { o[q] = (short)u0[q]; o[q + 4] = (short)u1[q]; }
    *(short8*)(Wout + (size_t)(n0 + nl) * K + k0 + kc) = o;
  }
}

// ---------------------------------------------------------------------------
// Kernel 4: gather + convert x rows into permuted bf16 [PADMAX][DIM]
// ---------------------------------------------------------------------------
__global__ __launch_bounds__(256)
void xgather_kernel(const float* __restrict__ x, const int* __restrict__ perm,
                    unsigned short* __restrict__ xg) {
  const int slot = blockIdx.x;
  const int t    = perm[slot];
  const int tid  = threadIdx.x;
  ushort4v o = (ushort4v){0, 0, 0, 0};
  if (t >= 0) {
    const float4v v = *(const float4v*)(x + (size_t)t * DIM + tid * 4);
#pragma unroll
    for (int q = 0; q < 4; q++) o[q] = f2bf(v[q]);
  }
  *(ushort4v*)(xg + (size_t)slot * DIM + tid * 4) = o;
}

// ---------------------------------------------------------------------------
// Kernel 5: h = gelu(xg @ W1T^T + b1) -> bf16. 256x128 tile, BK=64, 8 waves.
// ---------------------------------------------------------------------------
__global__ __launch_bounds__(NTHR)
void gemm1_kernel(const unsigned short* __restrict__ xg,
                  const unsigned short* __restrict__ W1T,
                  const float* __restrict__ b1, const int* __restrict__ tile_e,
                  unsigned short* __restrict__ h) {
  const int te = tile_e[blockIdx.x];
  if (te < 0) return;
  const unsigned short* Asrc = xg + (size_t)blockIdx.x * BM * DIM;
  const unsigned short* Bsrc = W1T + (size_t)te * DIM * DMLP + (size_t)(blockIdx.y * BN) * DIM;
  const int tid = threadIdx.x;

  __shared__ __align__(16) unsigned short As[BM * BK];   // 32 KB
  __shared__ __align__(16) unsigned short Bs[BN * BK];   // 16 KB

  const unsigned short* ag[4];
  const unsigned short* bg[2];
  int alo[4], blo[2];
#pragma unroll
  for (int t = 0; t < 4; t++) {
    const int p = t * NTHR + tid;
    const int r = p >> 3;
    const int c = (p & 7) ^ (r & 7);
    ag[t] = Asrc + (size_t)r * DIM + c * 8;
    alo[t] = p * 8;
  }
#pragma unroll
  for (int t = 0; t < 2; t++) {
    const int p = t * NTHR + tid;
    const int r = p >> 3;
    const int c = (p & 7) ^ (r & 7);
    bg[t] = Bsrc + (size_t)r * DIM + c * 8;
    blo[t] = p * 8;
  }

  const int wid = tid >> 6, lane = tid & 63;
  const int wm = (wid >> 1) * 64, wn = (wid & 1) * 64;
  const int l15 = lane & 15, quad = lane >> 4;

  float4v acc[4][4];
#pragma unroll
  for (int i = 0; i < 4; i++)
#pragma unroll
    for (int j = 0; j < 4; j++) acc[i][j] = (float4v){0.f, 0.f, 0.f, 0.f};

  for (int k0 = 0; k0 < DIM; k0 += BK) {
#pragma unroll
    for (int t = 0; t < 4; t++) ASYNC16(ag[t] + k0, &As[alo[t]]);
#pragma unroll
    for (int t = 0; t < 2; t++) ASYNC16(bg[t] + k0, &Bs[blo[t]]);
    __syncthreads();

#pragma unroll
    for (int hh = 0; hh < 2; hh++) {
      short8 a[4], b[4];
      const int C = hh * 4 + quad;
#pragma unroll
      for (int i = 0; i < 4; i++) a[i] = *(const short8*)&As[FRAG_OFF(wm + i * 16 + l15, C)];
#pragma unroll
      for (int j = 0; j < 4; j++) b[j] = *(const short8*)&Bs[FRAG_OFF(wn + j * 16 + l15, C)];
#pragma unroll
      for (int i = 0; i < 4; i++)
#pragma unroll
        for (int j = 0; j < 4; j++)
          acc[i][j] = __builtin_amdgcn_mfma_f32_16x16x32_bf16(a[i], b[j], acc[i][j], 0, 0, 0);
    }
    __syncthreads();
  }

#pragma unroll
  for (int i = 0; i < 4; i++) {
#pragma unroll
    for (int j = 0; j < 4; j++) {
      const int col = blockIdx.y * BN + wn + j * 16 + l15;
      const float bias = b1[te * DMLP + col];
#pragma unroll
      for (int r = 0; r < 4; r++) {
        const int row = wm + i * 16 + quad * 4 + r;
        const float v = gelu_f(acc[i][j][r] + bias);
        h[(size_t)(blockIdx.x * BM + row) * DMLP + col] = f2bf(v);
      }
    }
  }
}

// ---------------------------------------------------------------------------
// Kernel 6: out[tok] += h @ W2T^T (+ b2 on kz==0). 256x128 tile, split-K x4.
// ---------------------------------------------------------------------------
__global__ __launch_bounds__(NTHR)
void gemm2_kernel(const unsigned short* __restrict__ h,
                  const unsigned short* __restrict__ W2T,
                  const float* __restrict__ b2, const int* __restrict__ perm,
                  const int* __restrict__ tile_e, float* __restrict__ out) {
  const int te = tile_e[blockIdx.x];
  if (te < 0) return;
  const int kbase = blockIdx.z * KCHUNK;
  const unsigned short* Asrc = h + (size_t)blockIdx.x * BM * DMLP + kbase;
  const unsigned short* Bsrc = W2T + (size_t)te * DMLP * DIM
                             + (size_t)(blockIdx.y * BN) * DMLP + kbase;
  const int tid = threadIdx.x;

  __shared__ __align__(16) unsigned short As[BM * BK];   // 32 KB
  __shared__ __align__(16) unsigned short Bs[BN * BK];   // 16 KB

  const unsigned short* ag[4];
  const unsigned short* bg[2];
  int alo[4], blo[2];
#pragma unroll
  for (int t = 0; t < 4; t++) {
    const int p = t * NTHR + tid;
    const int r = p >> 3;
    const int c = (p & 7) ^ (r & 7);
    ag[t] = Asrc + (size_t)r * DMLP + c * 8;
    alo[t] = p * 8;
  }
#pragma unroll
  for (int t = 0; t < 2; t++) {
    const int p = t * NTHR + tid;
    const int r = p >> 3;
    const int c = (p & 7) ^ (r & 7);
    bg[t] = Bsrc + (size_t)r * DMLP + c * 8;
    blo[t] = p * 8;
  }

  const int wid = tid >> 6, lane = tid & 63;
  const int wm = (wid >> 1) * 64, wn = (wid & 1) * 64;
  const int l15 = lane & 15, quad = lane >> 4;

  float4v acc[4][4];
#pragma unroll
  for (int i = 0; i < 4; i++)
#pragma unroll
    for (int j = 0; j < 4; j++) acc[i][j] = (float4v){0.f, 0.f, 0.f, 0.f};

  for (int k0 = 0; k0 < KCHUNK; k0 += BK) {
#pragma unroll
    for (int t = 0; t < 4; t++) ASYNC16(ag[t] + k0, &As[alo[t]]);
#pragma unroll
    for (int t = 0; t < 2; t++) ASYNC16(bg[t] + k0, &Bs[blo[t]]);
    __syncthreads();

#pragma unroll
    for (int hh = 0; hh < 2; hh++) {
      short8 a[4], b[4];
      const int C = hh * 4 + quad;
#pragma unroll
      for (int i = 0; i < 4; i++) a[i] = *(const short8*)&As[FRAG_OFF(wm + i * 16 + l15, C)];
#pragma unroll
      for (int j = 0; j < 4; j++) b[j] = *(const short8*)&Bs[FRAG_OFF(wn + j * 16 + l15, C)];
#pragma unroll
      for (int i = 0; i < 4; i++)
#pragma unroll
        for (int j = 0; j < 4; j++)
          acc[i][j] = __builtin_amdgcn_mfma_f32_16x16x32_bf16(a[i], b[j], acc[i][j], 0, 0, 0);
    }
    __syncthreads();
  }

#pragma unroll
  for (int i = 0; i < 4; i++) {
#pragma unroll
    for (int j = 0; j < 4; j++) {
      const int col = blockIdx.y * BN + wn + j * 16 + l15;
      const float bias = (blockIdx.z == 0) ? b2[te * DIM + col] : 0.f;
#pragma unroll
      for (int r = 0; r < 4; r++) {
        const int row  = wm + i * 16 + quad * 4 + r;
        const int slot = blockIdx.x * BM + row;
        const int t    = perm[slot];
        if (t >= 0) atomicAdd(&out[(size_t)t * DIM + col], acc[i][j][r] + bias);
      }
    }
  }
}

// ---------------------------------------------------------------------------
extern "C" void kernel_launch(void* const* d_in, const int* in_sizes, int n_in,
                              void* d_out, int out_size, void* d_ws, size_t ws_size,
                              hipStream_t stream) {
  const float* x    = (const float*)d_in[0];
  const int*   eidx = (const int*)d_in[1];
  const float* W1   = (const float*)d_in[2];
  const float* b1   = (const float*)d_in[3];
  const float* W2   = (const float*)d_in[4];
  const float* b2   = (const float*)d_in[5];
  float* out = (float*)d_out;

  char* ws = (char*)d_ws;
  int* perm   = (int*)ws;                              // PADMAX ints
  int* tile_e = (int*)(ws + PADMAX * sizeof(int));     // NTILES ints
  unsigned short* xg  = (unsigned short*)(ws + 32768);                       // 12.6 MB
  unsigned short* h   = (unsigned short*)((char*)xg + (size_t)PADMAX * DIM * 2);   // 50.3 MB
  unsigned short* W1T = (unsigned short*)((char*)h + (size_t)PADMAX * DMLP * 2);   // 64 MB
  unsigned short* W2T = (unsigned short*)((char*)W1T + (size_t)NE * DIM * DMLP * 2); // 64 MB

  group_kernel<<<1, 256, 0, stream>>>(eidx, perm, tile_e);
  zero_out_kernel<<<(TOK * DIM) / 1024, 256, 0, stream>>>(out);
  convtrans_kernel<<<dim3(DMLP / 64, DIM / 64, NE), 256, 0, stream>>>(W1, W1T, DIM, DMLP);
  convtrans_kernel<<<dim3(DIM / 64, DMLP / 64, NE), 256, 0, stream>>>(W2, W2T, DMLP, DIM);
  xgather_kernel<<<PADMAX, 256, 0, stream>>>(x, perm, xg);
  gemm1_kernel<<<dim3(NTILES, DMLP / BN), NTHR, 0, stream>>>(xg, W1T, b1, tile_e, h);
  gemm2_kernel<<<dim3(NTILES, DIM / BN, KSPLIT), NTHR, 0, stream>>>(h, W2T, b2, perm, tile_e, out);
}